// Round 3
// baseline (646.763 us; speedup 1.0000x reference)
//
#include <hip/hip_runtime.h>

// ---------------- types ----------------
typedef __bf16 bf16;
typedef __bf16 bf16x4 __attribute__((ext_vector_type(4)));
typedef __bf16 bf16x8 __attribute__((ext_vector_type(8)));
typedef float  f32x4  __attribute__((ext_vector_type(4)));

// Problem constants: b=64, a=8 -> 512 slices total, processed in 2 groups of SG=256.
// f=F=256 (DIM), t=T=256, 3*hidden=1536, heads=4, c=128
#define TT    256
#define FF    256
#define SG    256         // slices per group
#define NGRP  2

static __device__ inline f32x4 mfma16(bf16x8 a, bf16x8 b, f32x4 c) {
    return __builtin_amdgcn_mfma_f32_16x16x32_bf16(a, b, c, 0, 0, 0);
}

// ---- async global->LDS staging (16B per lane; LDS dest = wave-uniform base + lane*16) ----
typedef const __attribute__((address_space(1))) unsigned int* gp_t;
typedef __attribute__((address_space(3))) unsigned int* lp_t;
static __device__ inline void gll16(const bf16* g, bf16* l) {
    __builtin_amdgcn_global_load_lds((gp_t)g, (lp_t)l, 16, 0, 0);
}

// Stage [128][32] bf16 tile (row-major global, leading dim ld elts) -> unpadded LDS [128][32].
// 4 waves; wave w stages rows [w*32, w*32+32) via 2 instrs (16 rows per instr).
static __device__ inline void stage128g(const bf16* __restrict__ g, int ld, bf16* __restrict__ l) {
    int lane = threadIdx.x & 63, wv = threadIdx.x >> 6;
    int r = lane >> 2, c8 = (lane & 3) * 8;
#pragma unroll
    for (int i = 0; i < 2; i++) {
        int row0 = wv * 32 + i * 16;
        gll16(g + (size_t)(row0 + r) * ld + c8, l + row0 * 32);
    }
}
// Fragment load from unpadded [rows][32] tile: lane holds row (row0 + lane&15), k = (lane>>4)*8 + j
static __device__ inline bf16x8 fragld(const bf16* __restrict__ l, int row0) {
    int lane = threadIdx.x & 63;
    return *(const bf16x8*)(l + (row0 + (lane & 15)) * 32 + (lane >> 4) * 8);
}
// Same but explicit stride (for the ct LDS round-trip in k_attn)
static __device__ inline bf16x8 fragld_s(const bf16* __restrict__ l, int row0, int stride) {
    int lane = threadIdx.x & 63;
    return *(const bf16x8*)(l + (row0 + (lane & 15)) * stride + (lane >> 4) * 8);
}

// ---------------- small prep kernels ----------------
// fp32 -> bf16, 4 elts/thread, grid = n/1024 exactly
__global__ __launch_bounds__(256) void k_cvt(const float4* __restrict__ src, bf16* __restrict__ dst) {
    int i = blockIdx.x * 256 + threadIdx.x;
    float4 v = src[i];
    bf16x4 o;
    o[0] = (__bf16)v.x; o[1] = (__bf16)v.y; o[2] = (__bf16)v.z; o[3] = (__bf16)v.w;
    *(bf16x4*)(dst + (size_t)i * 4) = o;
}

// mish(time) fp32 -> bf16, layout [512][256]; grid 128 (4 elts/thread)
__global__ __launch_bounds__(256) void k_mish(const float4* __restrict__ src, bf16* __restrict__ dst) {
    int i = blockIdx.x * 256 + threadIdx.x;
    float4 v = src[i];
    float in[4] = {v.x, v.y, v.z, v.w};
    bf16x4 o;
#pragma unroll
    for (int j = 0; j < 4; j++) {
        float sp = log1pf(__expf(in[j]));
        o[j] = (__bf16)(in[j] * tanhf(sp));
    }
    *(bf16x4*)(dst + (size_t)i * 4) = o;
}

// x [s][f][t] fp32 -> xT [s][t][f] bf16 (64x64 LDS tiles); grid = SG*16, s is group-local
__global__ __launch_bounds__(256) void k_xpose(const float* __restrict__ x, bf16* __restrict__ xT) {
    __shared__ float tile[64][65];
    int bid = blockIdx.x;
    int s  = bid >> 4;
    int f0 = ((bid >> 2) & 3) * 64;
    int t0 = (bid & 3) * 64;
    int tid = threadIdx.x;
    int rr = tid >> 4;           // 0..15
    int cc = (tid & 15) * 4;     // 0..60
    const float* xp = x + ((size_t)(s * FF + f0)) * TT + t0;
#pragma unroll
    for (int i = 0; i < 4; i++) {
        int r = i * 16 + rr;
        float4 v = *(const float4*)(xp + (size_t)r * TT + cc);
        tile[r][cc] = v.x; tile[r][cc + 1] = v.y; tile[r][cc + 2] = v.z; tile[r][cc + 3] = v.w;
    }
    __syncthreads();
    bf16* op = xT + ((size_t)(s * TT + t0)) * FF + f0;
#pragma unroll
    for (int i = 0; i < 4; i++) {
        int tr = i * 16 + rr;
        bf16x4 o;
        o[0] = (__bf16)tile[cc][tr];     o[1] = (__bf16)tile[cc + 1][tr];
        o[2] = (__bf16)tile[cc + 2][tr]; o[3] = (__bf16)tile[cc + 3][tr];
        *(bf16x4*)(op + (size_t)tr * FF + cc) = o;
    }
}

// ---------------- temb GEMM: tembT[o][sg] = w_time[o][:] . mish[sg][:] + b_time[o] ----------------
// grid (12, 4), Mtile=128(o), Ntile=128(sg over all 512), K=256. Runs once.
// 2-phase prefetch: issue next K-tile's global_load_lds before computing current;
// trailing __syncthreads (vmcnt(0)+lgkmcnt(0)+barrier) overlaps load latency w/ compute.
__global__ __launch_bounds__(256) void k_temb(const bf16* __restrict__ wt, const bf16* __restrict__ mish,
                                              const float* __restrict__ bt, float* __restrict__ tembT) {
    __shared__ bf16 lA[2][128 * 32];
    __shared__ bf16 lB[2][128 * 32];
    int o0 = blockIdx.x * 128, s0 = blockIdx.y * 128;
    int tid = threadIdx.x, wv = tid >> 6, lane = tid & 63, qd = lane >> 4, c = lane & 15;
    f32x4 acc[2][8] = {};
    stage128g(wt + (size_t)o0 * 256, 256, lA[0]);
    stage128g(mish + (size_t)s0 * 256, 256, lB[0]);
    __syncthreads();
    int cur = 0;
    for (int k0 = 0; k0 < 256; k0 += 32) {
        if (k0 + 32 < 256) {
            stage128g(wt + (size_t)o0 * 256 + k0 + 32, 256, lA[cur ^ 1]);
            stage128g(mish + (size_t)s0 * 256 + k0 + 32, 256, lB[cur ^ 1]);
        }
        bf16x8 a0 = fragld(lA[cur], wv * 32), a1 = fragld(lA[cur], wv * 32 + 16);
#pragma unroll
        for (int nt = 0; nt < 8; nt++) {
            bf16x8 b = fragld(lB[cur], nt * 16);
            acc[0][nt] = mfma16(a0, b, acc[0][nt]);
            acc[1][nt] = mfma16(a1, b, acc[1][nt]);
        }
        __syncthreads();
        cur ^= 1;
    }
#pragma unroll
    for (int mt = 0; mt < 2; mt++)
#pragma unroll
        for (int nt = 0; nt < 8; nt++)
#pragma unroll
            for (int r = 0; r < 4; r++) {
                int o = o0 + wv * 32 + mt * 16 + qd * 4 + r;
                int s = s0 + nt * 16 + c;
                tembT[(size_t)o * 512 + s] = acc[mt][nt][r] + bt[o];
            }
}

// ---------------- qkv GEMM ----------------
// Flat grid 24*SG. Bijective XCD-chunk swizzle (block b -> XCD b%8; each XCD gets a
// contiguous run of work ids so all 24 blocks of a slice share that XCD's L2 copy of xT).
// Work id w: s = w/24, j = w%24; oc = j>>1 (128-row o-chunk 0..11), th = j&1 (t-half).
// Per block: D[128 o][128 t] = W[o][f] xT[t][f] + temb. acc[2][8]; 2-phase prefetch.
// q -> qT[s][h][t][d] ; k,v -> [s][h][d][t]. tembT pre-offset by group column.
__global__ __launch_bounds__(256) void k_qkv(const bf16* __restrict__ wq, const bf16* __restrict__ xT,
                                             const float* __restrict__ tembT,
                                             bf16* __restrict__ qt, bf16* __restrict__ kk, bf16* __restrict__ vv) {
    __shared__ bf16 lA[2][128 * 32];
    __shared__ bf16 lB[2][128 * 32];
    int b = blockIdx.x;
    int w = (b & 7) * (24 * SG / 8) + (b >> 3);   // XCD chunking, 24*SG % 8 == 0
    int s = w / 24, j = w - s * 24;
    int oc = j >> 1, th = j & 1;
    int o0 = oc * 128, t0 = th * 128;
    int tid = threadIdx.x, wv = tid >> 6, lane = tid & 63, qd = lane >> 4, c = lane & 15;
    const bf16* xs = xT + (size_t)s * (TT * FF) + (size_t)t0 * FF;
    f32x4 acc[2][8] = {};
    stage128g(wq + (size_t)o0 * 256, 256, lA[0]);
    stage128g(xs, 256, lB[0]);
    __syncthreads();
    int cur = 0;
    for (int k0 = 0; k0 < 256; k0 += 32) {
        if (k0 + 32 < 256) {
            stage128g(wq + (size_t)o0 * 256 + k0 + 32, 256, lA[cur ^ 1]);
            stage128g(xs + k0 + 32, 256, lB[cur ^ 1]);
        }
        bf16x8 a0 = fragld(lA[cur], wv * 32), a1 = fragld(lA[cur], wv * 32 + 16);
#pragma unroll
        for (int nt = 0; nt < 8; nt++) {
            bf16x8 bfr = fragld(lB[cur], nt * 16);
            acc[0][nt] = mfma16(a0, bfr, acc[0][nt]);
            acc[1][nt] = mfma16(a1, bfr, acc[1][nt]);
        }
        __syncthreads();
        cur ^= 1;
    }
    int sec = oc >> 2, h = oc & 3;
    float tb[2][4];
#pragma unroll
    for (int mt = 0; mt < 2; mt++)
#pragma unroll
        for (int r = 0; r < 4; r++)
            tb[mt][r] = tembT[(size_t)(o0 + wv * 32 + mt * 16 + qd * 4 + r) * 512 + s];
    if (sec == 0) {
#pragma unroll
        for (int mt = 0; mt < 2; mt++)
#pragma unroll
            for (int nt = 0; nt < 8; nt++) {
                int t = t0 + nt * 16 + c, dl = wv * 32 + mt * 16 + qd * 4;
                bf16x4 o;
#pragma unroll
                for (int r = 0; r < 4; r++) o[r] = (__bf16)(acc[mt][nt][r] + tb[mt][r]);
                *(bf16x4*)(qt + (((size_t)s * 4 + h) * 256 + t) * 128 + dl) = o;
            }
    } else {
        bf16* dst0 = (sec == 1 ? kk : vv);
#pragma unroll
        for (int mt = 0; mt < 2; mt++)
#pragma unroll
            for (int nt = 0; nt < 8; nt++) {
                int t = t0 + nt * 16 + c, dl = wv * 32 + mt * 16 + qd * 4;
                bf16* d = dst0 + (((size_t)s * 4 + h) * 128 + dl) * 256 + t;
#pragma unroll
                for (int r = 0; r < 4; r++) d[(size_t)r * 256] = (__bf16)(acc[mt][nt][r] + tb[mt][r]);
            }
    }
}

// ---------------- fused attention per (s_local, h) ----------------
// grid SG*4. softmax(k) stats + ct = v expk^T + out = ct q. Writes midT[s][t][h*128+e].
// All staged loops 2-phase prefetched; phase-2 prologue hidden under phase-1 stats;
// phase-3b prologue hidden under the ct->LDS write-back.
// NOTE: no local arrays of LDS pointers (hipcc "static initializer addrspacecast" bug)
// -> buffer pointers are computed at each use site via byte offsets.
#define SM_LA2(i) ((bf16*)(smem + 1024 + (size_t)(i) * 8192))            // v tiles
#define SM_LB2(i) ((bf16*)(smem + 1024 + 16384 + (size_t)(i) * 8192))    // k tiles
#define SM_LQ(i)  ((bf16*)(smem + 1024 + (size_t)(i) * 8192))            // q tiles (alias v)
__global__ __launch_bounds__(256) void k_attn(const bf16* __restrict__ kk, const bf16* __restrict__ vv,
                                              const bf16* __restrict__ qt, bf16* __restrict__ midT) {
    __shared__ __align__(16) char smem[68608];
    float* mx = (float*)smem;                    // [128]
    float* rs = mx + 128;                        // [128]
    bf16* lct = (bf16*)(smem + 1024 + 32768);    // ct [128][136]  (34816 B, ends 68608)
    int bid = blockIdx.x;
    int s = bid >> 2, h = bid & 3;
    size_t base = ((size_t)s * 4 + h) * 32768;   // 128*256
    const bf16* kb = kk + base;
    const bf16* vb = vv + base;
    int tid = threadIdx.x, wv = tid >> 6, lane = tid & 63, qd = lane >> 4, c = lane & 15;

    // issue phase-2 tile-0 stage now; its latency hides under phase-1 stats compute
    stage128g(vb, 256, SM_LA2(0));
    stage128g(kb, 256, SM_LB2(0));

    // phase 1: softmax stats per k-row (online max/sum), 2 threads per row
    {
        int d = tid >> 1, half = tid & 1;
        const bf16* p = kb + (size_t)d * 256 + half * 128;
        float m = -3e38f, l = 0.f;
#pragma unroll
        for (int ci = 0; ci < 16; ci++) {
            bf16x8 v8 = *(const bf16x8*)(p + ci * 8);
            float xv[8]; float cm = -3e38f;
#pragma unroll
            for (int j = 0; j < 8; j++) { xv[j] = (float)v8[j]; cm = fmaxf(cm, xv[j]); }
            if (cm > m) { l *= __expf(m - cm); m = cm; }
#pragma unroll
            for (int j = 0; j < 8; j++) l += __expf(xv[j] - m);
        }
        float mo = __shfl_xor(m, 1);
        float lo = __shfl_xor(l, 1);
        float M = fmaxf(m, mo);
        float L = l * __expf(m - M) + lo * __expf(mo - M);
        if (half == 0) { mx[d] = M; rs[d] = 1.0f / L; }
    }
    __syncthreads();   // mx/rs visible AND phase-2 tile 0 staged

    // phase 2: ct[e][d] = sum_t v[e,t] * exp(k[d,t]-mx[d])   (A=v, B=exp(k)); 2-phase
    f32x4 cacc[2][8] = {};
    int cur = 0;
    for (int k0 = 0; k0 < 256; k0 += 32) {
        if (k0 + 32 < 256) {
            stage128g(vb + k0 + 32, 256, SM_LA2(cur ^ 1));
            stage128g(kb + k0 + 32, 256, SM_LB2(cur ^ 1));
        }
        bf16x8 a0 = fragld(SM_LA2(cur), wv * 32), a1 = fragld(SM_LA2(cur), wv * 32 + 16);
#pragma unroll
        for (int nt = 0; nt < 8; nt++) {
            bf16x8 kf = fragld(SM_LB2(cur), nt * 16);
            float md = mx[nt * 16 + c];
            bf16x8 b;
#pragma unroll
            for (int j = 0; j < 8; j++) b[j] = (__bf16)__expf((float)kf[j] - md);
            cacc[0][nt] = mfma16(a0, b, cacc[0][nt]);
            cacc[1][nt] = mfma16(a1, b, cacc[1][nt]);
        }
        __syncthreads();
        cur ^= 1;
    }

    // phase 3b tile-0 prologue: stage q[t 0..128)[d 0..32) now, hide under 3a write-back.
    // Safe: last phase-2 barrier guaranteed all reads of the staging region completed.
    const bf16* qb = qt + base;
    stage128g(qb, 128, SM_LQ(0));

    // phase 3a: ct -> LDS [e][d] (stride 136), scaled by 1/sum
#pragma unroll
    for (int mt = 0; mt < 2; mt++)
#pragma unroll
        for (int nt = 0; nt < 8; nt++) {
            int d = nt * 16 + c;
            float rv = rs[d];
#pragma unroll
            for (int r = 0; r < 4; r++) {
                int e = wv * 32 + mt * 16 + qd * 4 + r;
                lct[e * 136 + d] = (__bf16)(cacc[mt][nt][r] * rv);
            }
        }
    __syncthreads();   // lct visible AND lQ[0] staged

    // phase 3b: out[e][t] = sum_d ct[e][d] q[d][t]  (B from qT[t][d]); two t-halves,
    // 8 staged sub-tiles (th,d0) double-buffered across the flattened sequence.
    cur = 0;
    for (int th = 0; th < 2; th++) {
        f32x4 oacc[2][8] = {};
        for (int d0 = 0; d0 < 128; d0 += 32) {
            int idx = th * 4 + (d0 >> 5);
            if (idx < 7) {
                int n = idx + 1, th2 = n >> 2, d02 = (n & 3) * 32;
                stage128g(qb + (size_t)th2 * 128 * 128 + d02, 128, SM_LQ(cur ^ 1));
            }
            bf16x8 a0 = fragld_s(lct + d0, wv * 32, 136), a1 = fragld_s(lct + d0, wv * 32 + 16, 136);
#pragma unroll
            for (int nt = 0; nt < 8; nt++) {
                bf16x8 qf = fragld(SM_LQ(cur), nt * 16);
                oacc[0][nt] = mfma16(a0, qf, oacc[0][nt]);
                oacc[1][nt] = mfma16(a1, qf, oacc[1][nt]);
            }
            __syncthreads();
            cur ^= 1;
        }
        // epilogue: midT[s][t][h*128 + e]
#pragma unroll
        for (int mt = 0; mt < 2; mt++)
#pragma unroll
            for (int nt = 0; nt < 8; nt++) {
                int t = th * 128 + nt * 16 + c;
                int e = wv * 32 + mt * 16 + qd * 4;
                bf16x4 o;
#pragma unroll
                for (int r = 0; r < 4; r++) o[r] = (__bf16)oacc[mt][nt][r];
                *(bf16x4*)(midT + ((size_t)s * 256 + t) * 512 + h * 128 + e) = o;
            }
    }
}

// ---------------- final conv: y[s][o][t] = w_out[o][:] . mid[:][t] + b_out[o] ----------------
// Flat grid 4*SG with XCD swizzle. j = w%4: oc = j>>1 (o-chunk), th = j&1 (t-half).
// Mtile=128, Ntile=128, K=512. acc[2][8]; 2-phase prefetch. y pre-offset by group.
__global__ __launch_bounds__(256) void k_out(const bf16* __restrict__ wo, const bf16* __restrict__ midT,
                                             const float* __restrict__ bo, float* __restrict__ y) {
    __shared__ bf16 lA[2][128 * 32];
    __shared__ bf16 lB[2][128 * 32];
    int b = blockIdx.x;
    int w = (b & 7) * (4 * SG / 8) + (b >> 3);    // XCD chunking, 4*SG % 8 == 0
    int s = w >> 2, j = w & 3;
    int o0 = (j >> 1) * 128, t0 = (j & 1) * 128;
    int tid = threadIdx.x, wv = tid >> 6, lane = tid & 63, qd = lane >> 4, c = lane & 15;
    const bf16* ms = midT + (size_t)s * 131072 + (size_t)t0 * 512;  // 256*512
    f32x4 acc[2][8] = {};
    stage128g(wo + (size_t)o0 * 512, 512, lA[0]);
    stage128g(ms, 512, lB[0]);
    __syncthreads();
    int cur = 0;
    for (int k0 = 0; k0 < 512; k0 += 32) {
        if (k0 + 32 < 512) {
            stage128g(wo + (size_t)o0 * 512 + k0 + 32, 512, lA[cur ^ 1]);
            stage128g(ms + k0 + 32, 512, lB[cur ^ 1]);
        }
        bf16x8 a0 = fragld(lA[cur], wv * 32), a1 = fragld(lA[cur], wv * 32 + 16);
#pragma unroll
        for (int nt = 0; nt < 8; nt++) {
            bf16x8 bfr = fragld(lB[cur], nt * 16);
            acc[0][nt] = mfma16(a0, bfr, acc[0][nt]);
            acc[1][nt] = mfma16(a1, bfr, acc[1][nt]);
        }
        __syncthreads();
        cur ^= 1;
    }
    float bb[2][4];
#pragma unroll
    for (int mt = 0; mt < 2; mt++)
#pragma unroll
        for (int r = 0; r < 4; r++)
            bb[mt][r] = bo[o0 + wv * 32 + mt * 16 + qd * 4 + r];
#pragma unroll
    for (int mt = 0; mt < 2; mt++)
#pragma unroll
        for (int nt = 0; nt < 8; nt++)
#pragma unroll
            for (int r = 0; r < 4; r++) {
                int o = o0 + wv * 32 + mt * 16 + qd * 4 + r;
                int t = t0 + nt * 16 + c;
                y[((size_t)(s * 256 + o)) * 256 + t] = acc[mt][nt][r] + bb[mt][r];
            }
}

// ---------------- launch ----------------
extern "C" void kernel_launch(void* const* d_in, const int* in_sizes, int n_in,
                              void* d_out, int out_size, void* d_ws, size_t ws_size,
                              hipStream_t stream) {
    const float* x      = (const float*)d_in[0];
    const float* time_  = (const float*)d_in[1];
    const float* w_qkv  = (const float*)d_in[2];
    const float* w_time = (const float*)d_in[3];
    const float* b_time = (const float*)d_in[4];
    const float* w_out  = (const float*)d_in[5];
    const float* b_out  = (const float*)d_in[6];
    float* y = (float*)d_out;
    char* ws = (char*)d_ws;

    // Workspace layout (total 273,678,336 B; ws_size = 512 MiB).
    bf16*  wqkv_bf  = (bf16*)(ws + 0);            //   786432 B
    bf16*  wtime_bf = (bf16*)(ws + 786432);       //   786432 B
    bf16*  wout_bf  = (bf16*)(ws + 1572864);      //   262144 B
    bf16*  mish_bf  = (bf16*)(ws + 1835008);      //   262144 B
    float* tembT    = (float*)(ws + 2097152);     //  3145728 B  [1536][512] global
    bf16*  qt       = (bf16*)(ws + 5242880);      // 67108864 B  per group
    bf16*  kk       = (bf16*)(ws + 72351744);     // 67108864 B
    bf16*  vv       = (bf16*)(ws + 139460608);    // 67108864 B
    bf16*  midT     = (bf16*)(ws + 206569472);    // 67108864 B (ends 273678336)
    bf16*  xT       = (bf16*)(ws + 206569472);    // 33554432 B (aliases midT first half;
                                                  //  xT dead before k_attn writes midT)

    // global prep (once)
    k_cvt<<<384, 256, 0, stream>>>((const float4*)w_qkv, wqkv_bf);    // 393216 elts
    k_cvt<<<384, 256, 0, stream>>>((const float4*)w_time, wtime_bf);  // 393216
    k_cvt<<<128, 256, 0, stream>>>((const float4*)w_out, wout_bf);    // 131072
    k_mish<<<128, 256, 0, stream>>>((const float4*)time_, mish_bf);   // 131072
    k_temb<<<dim3(12, 4), 256, 0, stream>>>(wtime_bf, mish_bf, b_time, tembT);

    // per-group pipeline
    for (int g = 0; g < NGRP; g++) {
        const float* xg = x + (size_t)g * SG * FF * TT;
        float*       yg = y + (size_t)g * SG * 256 * TT;
        const float* tg = tembT + (size_t)g * SG;             // column offset into [1536][512]
        k_xpose<<<SG * 16, 256, 0, stream>>>(xg, xT);
        k_qkv<<<24 * SG, 256, 0, stream>>>(wqkv_bf, xT, tg, qt, kk, vv);
        k_attn<<<SG * 4, 256, 0, stream>>>(kk, vv, qt, midT);
        k_out<<<4 * SG, 256, 0, stream>>>(wout_bf, midT, b_out, yg);
    }
}

// Round 4
// 616.638 us; speedup vs baseline: 1.0489x; 1.0489x over previous
//
#include <hip/hip_runtime.h>

// ---------------- types ----------------
typedef __bf16 bf16;
typedef __bf16 bf16x4 __attribute__((ext_vector_type(4)));
typedef __bf16 bf16x8 __attribute__((ext_vector_type(8)));
typedef float  f32x4  __attribute__((ext_vector_type(4)));

// Problem constants: b=64, a=8 -> 512 slices total, processed in 2 groups of SG=256.
// f=F=256 (DIM), t=T=256, 3*hidden=1536, heads=4, c=128
#define TT    256
#define FF    256
#define SG    256         // slices per group
#define NGRP  2

// scheduling primitives for the counted-vmcnt pipeline (T3+T4)
#define SCHED0 __builtin_amdgcn_sched_barrier(0)
#define BAR    __builtin_amdgcn_s_barrier()
#define WAITVM(N) asm volatile("s_waitcnt vmcnt(" #N ")" ::: "memory")
#define WAITLGKM0 asm volatile("s_waitcnt lgkmcnt(0)" ::: "memory")

static __device__ inline f32x4 mfma16(bf16x8 a, bf16x8 b, f32x4 c) {
    return __builtin_amdgcn_mfma_f32_16x16x32_bf16(a, b, c, 0, 0, 0);
}

// ---- async global->LDS staging (16B per lane; LDS dest = wave-uniform base + lane*16) ----
typedef const __attribute__((address_space(1))) unsigned int* gp_t;
typedef __attribute__((address_space(3))) unsigned int* lp_t;
static __device__ inline void gll16(const bf16* g, bf16* l) {
    __builtin_amdgcn_global_load_lds((gp_t)g, (lp_t)l, 16, 0, 0);
}

// Stage [128][32] bf16 tile (row-major global, leading dim ld elts) -> unpadded LDS [128][32].
// 4 waves; wave w stages rows [w*32, w*32+32) via 2 instrs (16 rows per instr).
// => 4 vmcnt-increments per {A,B} tile pair, 2 per single tile.
static __device__ inline void stage128g(const bf16* __restrict__ g, int ld, bf16* __restrict__ l) {
    int lane = threadIdx.x & 63, wv = threadIdx.x >> 6;
    int r = lane >> 2, c8 = (lane & 3) * 8;
#pragma unroll
    for (int i = 0; i < 2; i++) {
        int row0 = wv * 32 + i * 16;
        gll16(g + (size_t)(row0 + r) * ld + c8, l + row0 * 32);
    }
}
// Fragment load from unpadded [rows][32] tile: lane holds row (row0 + lane&15), k = (lane>>4)*8 + j
static __device__ inline bf16x8 fragld(const bf16* __restrict__ l, int row0) {
    int lane = threadIdx.x & 63;
    return *(const bf16x8*)(l + (row0 + (lane & 15)) * 32 + (lane >> 4) * 8);
}
// Same but explicit stride (for the ct LDS round-trip in k_attn)
static __device__ inline bf16x8 fragld_s(const bf16* __restrict__ l, int row0, int stride) {
    int lane = threadIdx.x & 63;
    return *(const bf16x8*)(l + (row0 + (lane & 15)) * stride + (lane >> 4) * 8);
}

// ---------------- small prep kernels ----------------
// fp32 -> bf16, 4 elts/thread, grid = n/1024 exactly
__global__ __launch_bounds__(256) void k_cvt(const float4* __restrict__ src, bf16* __restrict__ dst) {
    int i = blockIdx.x * 256 + threadIdx.x;
    float4 v = src[i];
    bf16x4 o;
    o[0] = (__bf16)v.x; o[1] = (__bf16)v.y; o[2] = (__bf16)v.z; o[3] = (__bf16)v.w;
    *(bf16x4*)(dst + (size_t)i * 4) = o;
}

// mish(time) fp32 -> bf16, layout [512][256]; grid 128 (4 elts/thread)
__global__ __launch_bounds__(256) void k_mish(const float4* __restrict__ src, bf16* __restrict__ dst) {
    int i = blockIdx.x * 256 + threadIdx.x;
    float4 v = src[i];
    float in[4] = {v.x, v.y, v.z, v.w};
    bf16x4 o;
#pragma unroll
    for (int j = 0; j < 4; j++) {
        float sp = log1pf(__expf(in[j]));
        o[j] = (__bf16)(in[j] * tanhf(sp));
    }
    *(bf16x4*)(dst + (size_t)i * 4) = o;
}

// x [s][f][t] fp32 -> xT [s][t][f] bf16 (64x64 LDS tiles); grid = SG*16, s is group-local
__global__ __launch_bounds__(256) void k_xpose(const float* __restrict__ x, bf16* __restrict__ xT) {
    __shared__ float tile[64][65];
    int bid = blockIdx.x;
    int s  = bid >> 4;
    int f0 = ((bid >> 2) & 3) * 64;
    int t0 = (bid & 3) * 64;
    int tid = threadIdx.x;
    int rr = tid >> 4;           // 0..15
    int cc = (tid & 15) * 4;     // 0..60
    const float* xp = x + ((size_t)(s * FF + f0)) * TT + t0;
#pragma unroll
    for (int i = 0; i < 4; i++) {
        int r = i * 16 + rr;
        float4 v = *(const float4*)(xp + (size_t)r * TT + cc);
        tile[r][cc] = v.x; tile[r][cc + 1] = v.y; tile[r][cc + 2] = v.z; tile[r][cc + 3] = v.w;
    }
    __syncthreads();
    bf16* op = xT + ((size_t)(s * TT + t0)) * FF + f0;
#pragma unroll
    for (int i = 0; i < 4; i++) {
        int tr = i * 16 + rr;
        bf16x4 o;
        o[0] = (__bf16)tile[cc][tr];     o[1] = (__bf16)tile[cc + 1][tr];
        o[2] = (__bf16)tile[cc + 2][tr]; o[3] = (__bf16)tile[cc + 3][tr];
        *(bf16x4*)(op + (size_t)tr * FF + cc) = o;
    }
}

// ---------------- temb GEMM: tembT[o][sg] = w_time[o][:] . mish[sg][:] + b_time[o] ----------------
// grid (12, 4). Runs once, tiny. Plain single-buffered 2-barrier loop (r1 form).
__global__ __launch_bounds__(256) void k_temb(const bf16* __restrict__ wt, const bf16* __restrict__ mish,
                                              const float* __restrict__ bt, float* __restrict__ tembT) {
    __shared__ bf16 lA[128 * 32];
    __shared__ bf16 lB[128 * 32];
    int o0 = blockIdx.x * 128, s0 = blockIdx.y * 128;
    int tid = threadIdx.x, wv = tid >> 6, lane = tid & 63, qd = lane >> 4, c = lane & 15;
    f32x4 acc[2][8] = {};
    for (int k0 = 0; k0 < 256; k0 += 32) {
        __syncthreads();
        stage128g(wt + (size_t)o0 * 256 + k0, 256, lA);
        stage128g(mish + (size_t)s0 * 256 + k0, 256, lB);
        __syncthreads();
        bf16x8 a0 = fragld(lA, wv * 32), a1 = fragld(lA, wv * 32 + 16);
#pragma unroll
        for (int nt = 0; nt < 8; nt++) {
            bf16x8 b = fragld(lB, nt * 16);
            acc[0][nt] = mfma16(a0, b, acc[0][nt]);
            acc[1][nt] = mfma16(a1, b, acc[1][nt]);
        }
    }
#pragma unroll
    for (int mt = 0; mt < 2; mt++)
#pragma unroll
        for (int nt = 0; nt < 8; nt++)
#pragma unroll
            for (int r = 0; r < 4; r++) {
                int o = o0 + wv * 32 + mt * 16 + qd * 4 + r;
                int s = s0 + nt * 16 + c;
                tembT[(size_t)o * 512 + s] = acc[mt][nt][r] + bt[o];
            }
}

// ---------------- qkv GEMM (counted-vmcnt pipeline) ----------------
// Flat grid 24*SG, bijective XCD-chunk swizzle. Work id w: s = w/24, j = w%24;
// oc = j>>1 (128-row o-chunk), th = j&1 (t-half). D[128 o][128 t] = W xT^T + temb.
// K-loop: dbuf LDS, raw barriers, counted s_waitcnt vmcnt(4) -- prefetch tile t+2
// issued after the trailing barrier stays IN FLIGHT across the next barrier (T3+T4).
__global__ __launch_bounds__(256) void k_qkv(const bf16* __restrict__ wq, const bf16* __restrict__ xT,
                                             const float* __restrict__ tembT,
                                             bf16* __restrict__ qt, bf16* __restrict__ kk, bf16* __restrict__ vv) {
    __shared__ bf16 lA[2][128 * 32];
    __shared__ bf16 lB[2][128 * 32];
    int b = blockIdx.x;
    int w = (b & 7) * (24 * SG / 8) + (b >> 3);   // XCD chunking, 24*SG % 8 == 0
    int s = w / 24, j = w - s * 24;
    int oc = j >> 1, th = j & 1;
    int o0 = oc * 128, t0 = th * 128;
    int tid = threadIdx.x, wv = tid >> 6, lane = tid & 63, qd = lane >> 4, c = lane & 15;
    const bf16* wA = wq + (size_t)o0 * 256;
    const bf16* xs = xT + (size_t)s * (TT * FF) + (size_t)t0 * FF;
    f32x4 acc[2][8] = {};
    // prologue: tiles 0 and 1 (issue order matters for vmcnt counting)
    stage128g(wA, 256, lA[0]);
    stage128g(xs, 256, lB[0]);
    SCHED0;
    stage128g(wA + 32, 256, lA[1]);
    stage128g(xs + 32, 256, lB[1]);
    SCHED0;
#pragma unroll
    for (int t = 0; t < 8; t++) {
        if (t == 7) { WAITVM(0); } else { WAITVM(4); }   // tile t landed; t+1 stays in flight
        SCHED0; BAR; SCHED0;
        bf16x8 a0 = fragld(lA[t & 1], wv * 32), a1 = fragld(lA[t & 1], wv * 32 + 16);
#pragma unroll
        for (int nt = 0; nt < 8; nt++) {
            bf16x8 bfr = fragld(lB[t & 1], nt * 16);
            acc[0][nt] = mfma16(a0, bfr, acc[0][nt]);
            acc[1][nt] = mfma16(a1, bfr, acc[1][nt]);
        }
        SCHED0; BAR; SCHED0;   // all waves done reading buf[t&1]
        if (t + 2 < 8) {
            stage128g(wA + (t + 2) * 32, 256, lA[t & 1]);
            stage128g(xs + (t + 2) * 32, 256, lB[t & 1]);
        }
        SCHED0;
    }
    int sec = oc >> 2, h = oc & 3;
    float tb[2][4];
#pragma unroll
    for (int mt = 0; mt < 2; mt++)
#pragma unroll
        for (int r = 0; r < 4; r++)
            tb[mt][r] = tembT[(size_t)(o0 + wv * 32 + mt * 16 + qd * 4 + r) * 512 + s];
    if (sec == 0) {
#pragma unroll
        for (int mt = 0; mt < 2; mt++)
#pragma unroll
            for (int nt = 0; nt < 8; nt++) {
                int t = t0 + nt * 16 + c, dl = wv * 32 + mt * 16 + qd * 4;
                bf16x4 o;
#pragma unroll
                for (int r = 0; r < 4; r++) o[r] = (__bf16)(acc[mt][nt][r] + tb[mt][r]);
                *(bf16x4*)(qt + (((size_t)s * 4 + h) * 256 + t) * 128 + dl) = o;
            }
    } else {
        bf16* dst0 = (sec == 1 ? kk : vv);
#pragma unroll
        for (int mt = 0; mt < 2; mt++)
#pragma unroll
            for (int nt = 0; nt < 8; nt++) {
                int t = t0 + nt * 16 + c, dl = wv * 32 + mt * 16 + qd * 4;
                bf16* d = dst0 + (((size_t)s * 4 + h) * 128 + dl) * 256 + t;
#pragma unroll
                for (int r = 0; r < 4; r++) d[(size_t)r * 256] = (__bf16)(acc[mt][nt][r] + tb[mt][r]);
            }
    }
}

// ---------------- fused attention per (s_local, h) ----------------
// grid SG*4. softmax(k) stats + ct = v expk^T + out = ct q. Writes midT[s][t][h*128+e].
// phase-2 and phase-3b use the counted-vmcnt pipeline; phase-2 tiles 0/1 staged
// before phase-1 (latency hidden under stats); 3b tiles 0/1 staged under the
// ct->LDS write-back with an lgkm-only barrier transition (vmcnt kept in flight).
#define SM_LA2(i) ((bf16*)(smem + 1024 + (size_t)(i) * 8192))            // v tiles
#define SM_LB2(i) ((bf16*)(smem + 1024 + 16384 + (size_t)(i) * 8192))    // k tiles
#define SM_LQ(i)  ((bf16*)(smem + 1024 + (size_t)(i) * 8192))            // q tiles (alias v)
__global__ __launch_bounds__(256) void k_attn(const bf16* __restrict__ kk, const bf16* __restrict__ vv,
                                              const bf16* __restrict__ qt, bf16* __restrict__ midT) {
    __shared__ __align__(16) char smem[68608];
    float* mx = (float*)smem;                    // [128]
    float* rs = mx + 128;                        // [128]
    bf16* lct = (bf16*)(smem + 1024 + 32768);    // ct [128][136]  (34816 B, ends 68608)
    int bid = blockIdx.x;
    int s = bid >> 2, h = bid & 3;
    size_t base = ((size_t)s * 4 + h) * 32768;   // 128*256
    const bf16* kb = kk + base;
    const bf16* vb = vv + base;
    int tid = threadIdx.x, wv = tid >> 6, lane = tid & 63, qd = lane >> 4, c = lane & 15;

    // phase-2 prologue: tiles 0 and 1; latency hides under phase-1 stats
    stage128g(vb, 256, SM_LA2(0));
    stage128g(kb, 256, SM_LB2(0));
    SCHED0;
    stage128g(vb + 32, 256, SM_LA2(1));
    stage128g(kb + 32, 256, SM_LB2(1));
    SCHED0;

    // phase 1: softmax stats per k-row (online max/sum), 2 threads per row
    {
        int d = tid >> 1, half = tid & 1;
        const bf16* p = kb + (size_t)d * 256 + half * 128;
        float m = -3e38f, l = 0.f;
#pragma unroll
        for (int ci = 0; ci < 16; ci++) {
            bf16x8 v8 = *(const bf16x8*)(p + ci * 8);
            float xv[8]; float cm = -3e38f;
#pragma unroll
            for (int j = 0; j < 8; j++) { xv[j] = (float)v8[j]; cm = fmaxf(cm, xv[j]); }
            if (cm > m) { l *= __expf(m - cm); m = cm; }
#pragma unroll
            for (int j = 0; j < 8; j++) l += __expf(xv[j] - m);
        }
        float mo = __shfl_xor(m, 1);
        float lo = __shfl_xor(l, 1);
        float M = fmaxf(m, mo);
        float L = l * __expf(m - M) + lo * __expf(mo - M);
        if (half == 0) { mx[d] = M; rs[d] = 1.0f / L; }
    }
    __syncthreads();   // mx/rs visible (drains vmcnt; tiles 0/1 are then in LDS)

    // phase 2: ct[e][d] = sum_t v[e,t] * exp(k[d,t]-mx[d]); counted-vmcnt loop.
    // After the phase-1 drain the first two waits are no-ops; steady state from t=2.
    f32x4 cacc[2][8] = {};
#pragma unroll
    for (int t = 0; t < 8; t++) {
        if (t == 7) { WAITVM(0); } else { WAITVM(4); }
        SCHED0; BAR; SCHED0;
        bf16x8 a0 = fragld(SM_LA2(t & 1), wv * 32), a1 = fragld(SM_LA2(t & 1), wv * 32 + 16);
#pragma unroll
        for (int nt = 0; nt < 8; nt++) {
            bf16x8 kf = fragld(SM_LB2(t & 1), nt * 16);
            float md = mx[nt * 16 + c];
            bf16x8 bb;
#pragma unroll
            for (int j = 0; j < 8; j++) bb[j] = (__bf16)__expf((float)kf[j] - md);
            cacc[0][nt] = mfma16(a0, bb, cacc[0][nt]);
            cacc[1][nt] = mfma16(a1, bb, cacc[1][nt]);
        }
        SCHED0; BAR; SCHED0;
        if (t + 2 < 8) {
            stage128g(vb + (t + 2) * 32, 256, SM_LA2(t & 1));
            stage128g(kb + (t + 2) * 32, 256, SM_LB2(t & 1));
        }
        SCHED0;
    }

    // 3b prologue: q tiles 0,1 (2 loads each) -> 4 outstanding; fly under 3a.
    // Safe: phase-2 iter-7's trailing barrier guaranteed all reads of the region done.
    const bf16* qb = qt + base;
    stage128g(qb, 128, SM_LQ(0));
    SCHED0;
    stage128g(qb + 32, 128, SM_LQ(1));
    SCHED0;

    // phase 3a: ct -> LDS [e][d] (stride 136), scaled by 1/sum
#pragma unroll
    for (int mt = 0; mt < 2; mt++)
#pragma unroll
        for (int nt = 0; nt < 8; nt++) {
            int d = nt * 16 + c;
            float rv = rs[d];
#pragma unroll
            for (int r = 0; r < 4; r++) {
                int e = wv * 32 + mt * 16 + qd * 4 + r;
                lct[e * 136 + d] = (__bf16)(cacc[mt][nt][r] * rv);
            }
        }
    // transition: lct visible to all, WITHOUT draining vmcnt (q prefetch stays in flight)
    WAITLGKM0;
    SCHED0; BAR; SCHED0;

    // phase 3b: out[e][t] = sum_d ct[e][d] q[d][t]; 8 flattened (th,d0) tiles,
    // 2 loads/tile. Waits: idx 0-3,6 -> vmcnt(2); idx 4,5 -> vmcnt(16) (the 16
    // th=0 epilogue stores sit in the window; smaller N = safe over-drain);
    // idx 7 -> vmcnt(0).
#pragma unroll
    for (int th = 0; th < 2; th++) {
        f32x4 oacc[2][8] = {};
#pragma unroll
        for (int dd = 0; dd < 4; dd++) {
            int idx = th * 4 + dd;
            int d0 = dd * 32;
            if (idx == 7)                    { WAITVM(0); }
            else if (idx == 4 || idx == 5)   { WAITVM(16); }
            else                             { WAITVM(2); }
            SCHED0; BAR; SCHED0;
            bf16x8 a0 = fragld_s(lct + d0, wv * 32, 136), a1 = fragld_s(lct + d0, wv * 32 + 16, 136);
#pragma unroll
            for (int nt = 0; nt < 8; nt++) {
                bf16x8 qf = fragld(SM_LQ(idx & 1), nt * 16);
                oacc[0][nt] = mfma16(a0, qf, oacc[0][nt]);
                oacc[1][nt] = mfma16(a1, qf, oacc[1][nt]);
            }
            SCHED0; BAR; SCHED0;
            if (idx + 2 < 8) {
                int n = idx + 2;
                stage128g(qb + (size_t)(n >> 2) * 16384 + (n & 3) * 32, 128, SM_LQ(idx & 1));
            }
            SCHED0;
        }
        // epilogue: midT[s][t][h*128 + e]  (16 bf16x4 stores -> the vmcnt-window 16)
#pragma unroll
        for (int mt = 0; mt < 2; mt++)
#pragma unroll
            for (int nt = 0; nt < 8; nt++) {
                int t = th * 128 + nt * 16 + c;
                int e = wv * 32 + mt * 16 + qd * 4;
                bf16x4 o;
#pragma unroll
                for (int r = 0; r < 4; r++) o[r] = (__bf16)oacc[mt][nt][r];
                *(bf16x4*)(midT + ((size_t)s * 256 + t) * 512 + h * 128 + e) = o;
            }
    }
}

// ---------------- final conv: y[s][o][t] = w_out[o][:] . mid[:][t] + b_out[o] ----------------
// Flat grid 4*SG with XCD swizzle. Mtile=128, Ntile=128, K=512 (16 tiles),
// counted-vmcnt pipeline identical to k_qkv.
__global__ __launch_bounds__(256) void k_out(const bf16* __restrict__ wo, const bf16* __restrict__ midT,
                                             const float* __restrict__ bo, float* __restrict__ y) {
    __shared__ bf16 lA[2][128 * 32];
    __shared__ bf16 lB[2][128 * 32];
    int b = blockIdx.x;
    int w = (b & 7) * (4 * SG / 8) + (b >> 3);    // XCD chunking, 4*SG % 8 == 0
    int s = w >> 2, j = w & 3;
    int o0 = (j >> 1) * 128, t0 = (j & 1) * 128;
    int tid = threadIdx.x, wv = tid >> 6, lane = tid & 63, qd = lane >> 4, c = lane & 15;
    const bf16* wA = wo + (size_t)o0 * 512;
    const bf16* ms = midT + (size_t)s * 131072 + (size_t)t0 * 512;  // 256*512
    f32x4 acc[2][8] = {};
    stage128g(wA, 512, lA[0]);
    stage128g(ms, 512, lB[0]);
    SCHED0;
    stage128g(wA + 32, 512, lA[1]);
    stage128g(ms + 32, 512, lB[1]);
    SCHED0;
#pragma unroll
    for (int t = 0; t < 16; t++) {
        if (t == 15) { WAITVM(0); } else { WAITVM(4); }
        SCHED0; BAR; SCHED0;
        bf16x8 a0 = fragld(lA[t & 1], wv * 32), a1 = fragld(lA[t & 1], wv * 32 + 16);
#pragma unroll
        for (int nt = 0; nt < 8; nt++) {
            bf16x8 bfr = fragld(lB[t & 1], nt * 16);
            acc[0][nt] = mfma16(a0, bfr, acc[0][nt]);
            acc[1][nt] = mfma16(a1, bfr, acc[1][nt]);
        }
        SCHED0; BAR; SCHED0;
        if (t + 2 < 16) {
            stage128g(wA + (t + 2) * 32, 512, lA[t & 1]);
            stage128g(ms + (t + 2) * 32, 512, lB[t & 1]);
        }
        SCHED0;
    }
    float bb[2][4];
#pragma unroll
    for (int mt = 0; mt < 2; mt++)
#pragma unroll
        for (int r = 0; r < 4; r++)
            bb[mt][r] = bo[o0 + wv * 32 + mt * 16 + qd * 4 + r];
#pragma unroll
    for (int mt = 0; mt < 2; mt++)
#pragma unroll
        for (int nt = 0; nt < 8; nt++)
#pragma unroll
            for (int r = 0; r < 4; r++) {
                int o = o0 + wv * 32 + mt * 16 + qd * 4 + r;
                int t = t0 + nt * 16 + c;
                y[((size_t)(s * 256 + o)) * 256 + t] = acc[mt][nt][r] + bb[mt][r];
            }
}

// ---------------- launch ----------------
extern "C" void kernel_launch(void* const* d_in, const int* in_sizes, int n_in,
                              void* d_out, int out_size, void* d_ws, size_t ws_size,
                              hipStream_t stream) {
    const float* x      = (const float*)d_in[0];
    const float* time_  = (const float*)d_in[1];
    const float* w_qkv  = (const float*)d_in[2];
    const float* w_time = (const float*)d_in[3];
    const float* b_time = (const float*)d_in[4];
    const float* w_out  = (const float*)d_in[5];
    const float* b_out  = (const float*)d_in[6];
    float* y = (float*)d_out;
    char* ws = (char*)d_ws;

    // Workspace layout (total 273,678,336 B; ws_size = 512 MiB).
    bf16*  wqkv_bf  = (bf16*)(ws + 0);            //   786432 B
    bf16*  wtime_bf = (bf16*)(ws + 786432);       //   786432 B
    bf16*  wout_bf  = (bf16*)(ws + 1572864);      //   262144 B
    bf16*  mish_bf  = (bf16*)(ws + 1835008);      //   262144 B
    float* tembT    = (float*)(ws + 2097152);     //  3145728 B  [1536][512] global
    bf16*  qt       = (bf16*)(ws + 5242880);      // 67108864 B  per group
    bf16*  kk       = (bf16*)(ws + 72351744);     // 67108864 B
    bf16*  vv       = (bf16*)(ws + 139460608);    // 67108864 B
    bf16*  midT     = (bf16*)(ws + 206569472);    // 67108864 B (ends 273678336)
    bf16*  xT       = (bf16*)(ws + 206569472);    // 33554432 B (aliases midT first half;
                                                  //  xT dead before k_attn writes midT)

    // global prep (once)
    k_cvt<<<384, 256, 0, stream>>>((const float4*)w_qkv, wqkv_bf);    // 393216 elts
    k_cvt<<<384, 256, 0, stream>>>((const float4*)w_time, wtime_bf);  // 393216
    k_cvt<<<128, 256, 0, stream>>>((const float4*)w_out, wout_bf);    // 131072
    k_mish<<<128, 256, 0, stream>>>((const float4*)time_, mish_bf);   // 131072
    k_temb<<<dim3(12, 4), 256, 0, stream>>>(wtime_bf, mish_bf, b_time, tembT);

    // per-group pipeline
    for (int g = 0; g < NGRP; g++) {
        const float* xg = x + (size_t)g * SG * FF * TT;
        float*       yg = y + (size_t)g * SG * 256 * TT;
        const float* tg = tembT + (size_t)g * SG;             // column offset into [1536][512]
        k_xpose<<<SG * 16, 256, 0, stream>>>(xg, xT);
        k_qkv<<<24 * SG, 256, 0, stream>>>(wqkv_bf, xT, tg, qt, kk, vv);
        k_attn<<<SG * 4, 256, 0, stream>>>(kk, vv, qt, midT);
        k_out<<<4 * SG, 256, 0, stream>>>(wout_bf, midT, b_out, yg);
    }
}